// Round 18
// baseline (413.715 us; speedup 1.0000x reference)
//
#include <hip/hip_runtime.h>
#include <hip/hip_bf16.h>

typedef __attribute__((ext_vector_type(8))) short short8;
typedef __attribute__((ext_vector_type(4))) short short4v;
typedef __attribute__((ext_vector_type(4))) float floatx4;

static __device__ __forceinline__ unsigned short f2bf(float f){
  union { float f; unsigned int u; } v; v.f = f;
  return (unsigned short)((v.u + 0x7FFFu + ((v.u >> 16) & 1u)) >> 16);  // RNE
}
static __device__ __forceinline__ float bf2f(unsigned short b){
  union { unsigned int u; float f; } v; v.u = ((unsigned int)b) << 16; return v.f;
}
// packed cvt via compiler (v_cvt_pk_bf16_f32)
static __device__ __forceinline__ short8 cvt8_pk(floatx4 a, floatx4 b){
  union { __hip_bfloat162 h[4]; short8 s; } u;
  u.h[0] = __float22bfloat162_rn(float2{a[0], a[1]});
  u.h[1] = __float22bfloat162_rn(float2{a[2], a[3]});
  u.h[2] = __float22bfloat162_rn(float2{b[0], b[1]});
  u.h[3] = __float22bfloat162_rn(float2{b[2], b[3]});
  return u.s;
}
static __device__ __forceinline__ short4v cvt4(floatx4 a){
  union { __hip_bfloat162 h[2]; short4v s; } u;
  u.h[0] = __float22bfloat162_rn(float2{a[0], a[1]});
  u.h[1] = __float22bfloat162_rn(float2{a[2], a[3]});
  return u.s;
}
// 256-byte LDS rows, XOR swizzle over all 16 slots
static __device__ __forceinline__ short8 frag_ld(const char* ldsbase, int row, int kbyte){
  return *(const short8*)(ldsbase + row*256 + (kbyte ^ ((row & 15) << 4)));
}
// 128-byte LDS rows, XOR swizzle (8 slots)
static __device__ __forceinline__ short8 frag_ld64(const char* base, int row, int kbyte){
  return *(const short8*)(base + row*128 + (kbyte ^ ((row & 7) << 4)));
}

// ---------------- K1 (merged): bid<16 -> x = relu(r@W1^T+b1) (bf16 out);
//                  bid>=16 -> r_ol = r@b2_2d^T (f32 out). K=512, 256x128 tile. ----------------
template<int ROWS>
static __device__ __forceinline__ void stage_tile(char* ldsbase, const float* __restrict__ src,
                                                  int ld, int tid){
  #pragma unroll
  for (int w = 0; w < ROWS/32; ++w){
    int g = w*512 + tid;
    int row = g >> 4, k8 = g & 15;
    const float* p = src + (size_t)row*ld + k8*8;
    floatx4 v0 = *(const floatx4*)p;
    floatx4 v1 = *(const floatx4*)(p+4);
    *(short8*)(ldsbase + row*256 + ((k8*16) ^ ((row & 15) << 4))) = cvt8_pk(v0, v1);
  }
}

__global__ __launch_bounds__(512)
void gemm_two(const float* __restrict__ r, const float* __restrict__ W1,
              const float* __restrict__ b1, const float* __restrict__ b2,
              unsigned short* __restrict__ x_bf, float* __restrict__ r_ol){
  __shared__ char smem[98304];
  char* At = smem;            // [256][128] bf16 swz
  char* Bt = smem + 65536;    // [128][128] bf16 swz
  const int tid  = threadIdx.x;
  const int lane = tid & 63, w = tid >> 6;
  const int wm = w & 3, wn = w >> 2;
  const int bid0 = blockIdx.x;
  const int mode = bid0 >> 4;            // 0: x-GEMM, 1: bias-GEMV
  const int bid  = bid0 & 15;
  const float* Bsrc = mode ? b2 : W1;
  const int t0 = (bid & 3) * 256;
  const int c0 = (bid >> 2) * 128;
  const int rbase = wm*64, cbase = wn*64;

  floatx4 acc[4][4];
  #pragma unroll
  for (int i=0;i<4;++i)
    #pragma unroll
    for (int j=0;j<4;++j) acc[i][j] = floatx4{0.f,0.f,0.f,0.f};

  for (int kb = 0; kb < 4; ++kb){
    __syncthreads();
    stage_tile<256>(At, r + (size_t)t0*512 + kb*128, 512, tid);
    stage_tile<128>(Bt, Bsrc + (size_t)c0*512 + kb*128, 512, tid);
    __syncthreads();
    #pragma unroll
    for (int ks = 0; ks < 4; ++ks){
      const int kbyte = (ks*32 + (lane>>4)*8) * 2;
      short8 af[4], bfr[4];
      #pragma unroll
      for (int mi=0; mi<4; ++mi) af[mi] = frag_ld(At, rbase + mi*16 + (lane&15), kbyte);
      #pragma unroll
      for (int ni=0; ni<4; ++ni) bfr[ni] = frag_ld(Bt, cbase + ni*16 + (lane&15), kbyte);
      #pragma unroll
      for (int mi=0; mi<4; ++mi)
        #pragma unroll
        for (int ni=0; ni<4; ++ni)
          acc[mi][ni] = __builtin_amdgcn_mfma_f32_16x16x32_bf16(af[mi], bfr[ni], acc[mi][ni], 0,0,0);
    }
  }
  #pragma unroll
  for (int mi=0; mi<4; ++mi){
    #pragma unroll
    for (int ni=0; ni<4; ++ni){
      #pragma unroll
      for (int rg=0; rg<4; ++rg){
        int t = t0 + rbase + mi*16 + (lane>>4)*4 + rg;
        int c = c0 + cbase + ni*16 + (lane&15);
        float v = acc[mi][ni][rg];
        if (mode == 0){
          v += b1[c]; v = v > 0.f ? v : 0.f;
          x_bf[(size_t)t*512 + c] = f2bf(v);
        } else {
          r_ol[(size_t)t*512 + c] = v;
        }
      }
    }
  }
}

// ---------------- K2: r11 structure, setprio removed (m190: hurts lockstep GEMM) ----------------
// Grid 256: xr=bid&7 (XCD), idx=bid>>3: m=idx&3, gh=idx>>2; g=xr+8*gh; ht=g&3, ns=g>>2.
// Block: M=256 x N=128, 32 n, BK=128 (kb2 0..3) -> 128 bodies. 8 waves (4M x 2N), tile 64x64.
__global__ __launch_bounds__(512)
void k2_fold(const unsigned short* __restrict__ xbf, const float* __restrict__ r,
             const float* __restrict__ W2, float* __restrict__ r_ol){
  __shared__ char smem[147456];  // A[256][256B] @0; B dbuf 2x[128][256B] @65536; RT2 bf16[32][256] @131072
  unsigned short* RT2 = (unsigned short*)(smem + 131072);
  const int tid  = threadIdx.x;
  const int lane = tid & 63, w = tid >> 6;
  const int wm = w & 3, wn = w >> 2;       // 8 waves: 4M x 2N, wave tile 64x64
  const int bid = blockIdx.x;
  const int xr = bid & 7, idx = bid >> 3;
  const int m  = idx & 3, gh = idx >> 2;   // gh 0..7
  const int g  = xr + 8*gh;                // 0..63
  const int ht = g & 3, ns = g >> 2;       // ns 0..15
  const int t0 = m*256, h0 = ht*128, n0 = ns*32;

  // prologue: RT2[n][row] = bf16(r[t0+row, n0+n])
  #pragma unroll
  for (int i = 0; i < 16; ++i){
    int e = i*512 + tid; int row = e >> 5, c = e & 31;
    RT2[c*256 + row] = f2bf(r[(size_t)(t0+row)*512 + n0 + c]);
  }

  floatx4 acc[4][4];
  #pragma unroll
  for (int i=0;i<4;++i)
    #pragma unroll
    for (int j=0;j<4;++j) acc[i][j] = floatx4{0.f,0.f,0.f,0.f};

  floatx4 lb[8];

  // A stage: coalesced. row=(tid>>4)+j*32, chunk=(tid&15) of 16B. Wave instr: 4 full rows.
  auto stageA = [&](int kb2){
    const int chunk = tid & 15, rbase_ = tid >> 4;
    #pragma unroll
    for (int j = 0; j < 8; ++j){
      const int row = rbase_ + j*32;
      short8 v = *(const short8*)(xbf + (size_t)(t0+row)*512 + kb2*128 + chunk*8);
      *(short8*)(smem + row*256 + (((chunk ^ (row & 15)) << 4))) = v;
    }
  };
  // B stage: coalesced. row=(tid>>5)+j*16, col=(tid&31)*16B. Wave instr: 2 full rows x 512B.
  auto issueB = [&](int n, int kb2){
    const int c16 = tid & 31, rb = tid >> 5;
    const float* base = W2 + (size_t)(n0+n)*512 + (size_t)kb2*128 + c16*4;
    #pragma unroll
    for (int j = 0; j < 8; ++j)
      lb[j] = *(const floatx4*)(base + (size_t)(h0 + rb + j*16)*262144);
  };
  auto cvtB = [&](char* Bb){
    const int c8 = tid & 31, rb = tid >> 5;
    #pragma unroll
    for (int j = 0; j < 8; ++j){
      const int row = rb + j*16;
      const int byte = (((c8 >> 1) ^ (row & 15)) << 4) | ((c8 & 1) << 3);
      *(short4v*)(Bb + row*256 + byte) = cvt4(lb[j]);
    }
  };
  auto compute_fold = [&](const char* Bb, int n){
    float rvv[4][4];
    #pragma unroll
    for (int mi = 0; mi < 4; ++mi){
      const int rrow = wm*64 + mi*16 + (lane>>4)*4;
      short4v tv = *(const short4v*)(RT2 + n*256 + rrow);
      #pragma unroll
      for (int j = 0; j < 4; ++j) rvv[mi][j] = bf2f((unsigned short)tv[j]);
    }
    floatx4 ct[4][4];
    #pragma unroll
    for (int ks = 0; ks < 4; ++ks){
      const int kbyte = ks*64 + (lane>>4)*16;
      short8 af[4], bfr[4];
      #pragma unroll
      for (int mi=0; mi<4; ++mi) af[mi] = frag_ld(smem, wm*64 + mi*16 + (lane&15), kbyte);
      #pragma unroll
      for (int ni=0; ni<4; ++ni) bfr[ni] = frag_ld(Bb, wn*64 + ni*16 + (lane&15), kbyte);
      #pragma unroll
      for (int mi=0; mi<4; ++mi)
        #pragma unroll
        for (int ni=0; ni<4; ++ni)
          ct[mi][ni] = __builtin_amdgcn_mfma_f32_16x16x32_bf16(
              af[mi], bfr[ni], (ks==0) ? floatx4{0.f,0.f,0.f,0.f} : ct[mi][ni], 0,0,0);
    }
    #pragma unroll
    for (int mi=0; mi<4; ++mi)
      #pragma unroll
      for (int ni=0; ni<4; ++ni){
        acc[mi][ni][0] += rvv[mi][0] * ct[mi][ni][0];
        acc[mi][ni][1] += rvv[mi][1] * ct[mi][ni][1];
        acc[mi][ni][2] += rvv[mi][2] * ct[mi][ni][2];
        acc[mi][ni][3] += rvv[mi][3] * ct[mi][ni][3];
      }
  };

  // prologue
  stageA(0);
  issueB(0, 0);
  cvtB(smem + 65536);
  __syncthreads();

  int cur = 0;
  for (int kb2 = 0; kb2 < 4; ++kb2){
    for (int n = 0; n < 32; ++n){
      const int bi = kb2*32 + n;
      if (bi < 127){
        const int nn = (n == 31) ? 0 : n + 1;
        const int nk = (n == 31) ? kb2 + 1 : kb2;
        issueB(nn, nk);
      }
      compute_fold(smem + 65536 + cur*32768, n);
      if (bi < 127) cvtB(smem + 65536 + (cur^1)*32768);
      __syncthreads();
      cur ^= 1;
    }
    if (kb2 < 3){
      stageA(kb2 + 1);   // A-LDS rewrite only at kb2 boundary, behind its own barrier
      __syncthreads();
    }
  }

  #pragma unroll
  for (int ni = 0; ni < 4; ++ni){
    const int h = h0 + wn*64 + ni*16 + (lane & 15);
    #pragma unroll
    for (int mi = 0; mi < 4; ++mi){
      #pragma unroll
      for (int rg = 0; rg < 4; ++rg){
        const int t = t0 + wm*64 + mi*16 + (lane >> 4)*4 + rg;
        atomicAdd(&r_ol[(size_t)t*512 + h], acc[mi][ni][rg]);
      }
    }
  }
}

// ---------------- K3: logits = r_ol @ Wout^T + bout (K=512), m SLOWEST ----------------
// Grid 1000: c = bid%250, m = bid/250 -> Wout streamed from HBM once, L3-hit after.
__global__ __launch_bounds__(512, 2)
void gemm_out(const float* __restrict__ Asrc, const float* __restrict__ Bsrc,
              const float* __restrict__ bias, float* __restrict__ out){
  __shared__ char smem[98304];   // A dbuf 2x[256][128B] swz, B dbuf 2x[128][128B] swz
  const int tid  = threadIdx.x;
  const int lane = tid & 63, w = tid >> 6;
  const int wm = w & 3, wn = w >> 2;
  const int bid = blockIdx.x;
  const int t0 = (bid / 250) * 256;
  const int c0 = (bid % 250) * 128;

  floatx4 acc[4][4];
  #pragma unroll
  for (int i=0;i<4;++i)
    #pragma unroll
    for (int j=0;j<4;++j) acc[i][j] = floatx4{0.f,0.f,0.f,0.f};

  floatx4 la[8], lb[4];
  const int r16 = tid >> 4, c4 = tid & 15;

  auto issue = [&](int s){
    const int K0 = s*64;
    #pragma unroll
    for (int it=0; it<8; ++it){
      int row = it*32 + r16;
      la[it] = *(const floatx4*)(Asrc + (size_t)(t0+row)*512 + K0 + c4*4);
    }
    #pragma unroll
    for (int it=0; it<4; ++it){
      int row = it*32 + r16;
      lb[it] = *(const floatx4*)(Bsrc + (size_t)(c0+row)*512 + K0 + c4*4);
    }
  };
  auto write_buf = [&](int buf){
    char* ad = smem + buf*32768;
    #pragma unroll
    for (int it=0; it<8; ++it){
      int row = it*32 + r16;
      *(short4v*)(ad + row*128 + ((c4*8) ^ ((row & 7) << 4))) = cvt4(la[it]);
    }
    char* bd = smem + 65536 + buf*16384;
    #pragma unroll
    for (int it=0; it<4; ++it){
      int row = it*32 + r16;
      *(short4v*)(bd + row*128 + ((c4*8) ^ ((row & 7) << 4))) = cvt4(lb[it]);
    }
  };
  auto compute = [&](int buf){
    const char* Ab = smem + buf*32768;
    const char* Bb = smem + 65536 + buf*16384;
    #pragma unroll
    for (int ks = 0; ks < 2; ++ks){
      const int kbyte = ks*64 + (lane >> 4)*16;
      short8 af[4], bfr[4];
      #pragma unroll
      for (int mi = 0; mi < 4; ++mi) af[mi] = frag_ld64(Ab, wm*64 + mi*16 + (lane&15), kbyte);
      #pragma unroll
      for (int ni = 0; ni < 4; ++ni) bfr[ni] = frag_ld64(Bb, wn*64 + ni*16 + (lane&15), kbyte);
      #pragma unroll
      for (int mi = 0; mi < 4; ++mi)
        #pragma unroll
        for (int ni = 0; ni < 4; ++ni)
          acc[mi][ni] = __builtin_amdgcn_mfma_f32_16x16x32_bf16(af[mi], bfr[ni], acc[mi][ni], 0,0,0);
    }
  };

  issue(0);
  write_buf(0);
  __syncthreads();
  for (int s = 0; s < 8; ++s){
    const int cur = s & 1;
    if (s < 7) issue(s + 1);
    compute(cur);
    if (s < 7){
      write_buf(cur ^ 1);
      __syncthreads();
    }
  }

  #pragma unroll
  for (int ni = 0; ni < 4; ++ni){
    const int c = c0 + wn*64 + ni*16 + (lane & 15);
    const float bv = bias[c];
    #pragma unroll
    for (int mi = 0; mi < 4; ++mi){
      #pragma unroll
      for (int rg = 0; rg < 4; ++rg){
        const int t = t0 + wm*64 + mi*16 + (lane >> 4)*4 + rg;
        out[(size_t)t*32000 + c] = acc[mi][ni][rg] + bv;
      }
    }
  }
}

extern "C" void kernel_launch(void* const* d_in, const int* in_sizes, int n_in,
                              void* d_out, int out_size, void* d_ws, size_t ws_size,
                              hipStream_t stream) {
  const float* r    = (const float*)d_in[0];   // [1024][512]
  const float* W1   = (const float*)d_in[1];   // [512][512]
  const float* b1   = (const float*)d_in[2];   // [512]
  const float* W2   = (const float*)d_in[3];   // [262144][512]
  const float* b2   = (const float*)d_in[4];   // [262144] == [512 h][512 n]
  const float* Wout = (const float*)d_in[5];   // [32000][512]
  const float* bout = (const float*)d_in[6];   // [32000]
  float* logits = (float*)d_out;               // [1024][32000]

  unsigned short* x_bf = (unsigned short*)d_ws;                 // 1 MiB bf16
  float* r_ol = (float*)((char*)d_ws + 1024*512*2);             // 2 MiB f32

  // merged: x = relu(r@W1^T+b1) -> bf16  AND  r_ol = r@b2_2d^T (atomic-target init)
  gemm_two<<<32, 512, 0, stream>>>(r, W1, b1, b2, x_bf, r_ol);
  // r_ol += fold-structured big GEMM (r11 structure, setprio removed)
  k2_fold<<<256, 512, 0, stream>>>(x_bf, r, W2, r_ol);
  // logits = r_ol @ Wout^T + bout (m-slowest for Wout L3 residency)
  gemm_out<<<1000, 512, 0, stream>>>(r_ol, Wout, bout, logits);
}

// Round 19
// 383.838 us; speedup vs baseline: 1.0778x; 1.0778x over previous
//
#include <hip/hip_runtime.h>
#include <hip/hip_bf16.h>

typedef __attribute__((ext_vector_type(8))) short short8;
typedef __attribute__((ext_vector_type(4))) short short4v;
typedef __attribute__((ext_vector_type(4))) float floatx4;

static __device__ __forceinline__ unsigned short f2bf(float f){
  union { float f; unsigned int u; } v; v.f = f;
  return (unsigned short)((v.u + 0x7FFFu + ((v.u >> 16) & 1u)) >> 16);  // RNE
}
static __device__ __forceinline__ float bf2f(unsigned short b){
  union { unsigned int u; float f; } v; v.u = ((unsigned int)b) << 16; return v.f;
}
// packed cvt via compiler (v_cvt_pk_bf16_f32)
static __device__ __forceinline__ short8 cvt8_pk(floatx4 a, floatx4 b){
  union { __hip_bfloat162 h[4]; short8 s; } u;
  u.h[0] = __float22bfloat162_rn(float2{a[0], a[1]});
  u.h[1] = __float22bfloat162_rn(float2{a[2], a[3]});
  u.h[2] = __float22bfloat162_rn(float2{b[0], b[1]});
  u.h[3] = __float22bfloat162_rn(float2{b[2], b[3]});
  return u.s;
}
static __device__ __forceinline__ short4v cvt4(floatx4 a){
  union { __hip_bfloat162 h[2]; short4v s; } u;
  u.h[0] = __float22bfloat162_rn(float2{a[0], a[1]});
  u.h[1] = __float22bfloat162_rn(float2{a[2], a[3]});
  return u.s;
}
// 256-byte LDS rows, XOR swizzle over all 16 slots
static __device__ __forceinline__ short8 frag_ld(const char* ldsbase, int row, int kbyte){
  return *(const short8*)(ldsbase + row*256 + (kbyte ^ ((row & 15) << 4)));
}
// 128-byte LDS rows, XOR swizzle (8 slots)
static __device__ __forceinline__ short8 frag_ld64(const char* base, int row, int kbyte){
  return *(const short8*)(base + row*128 + (kbyte ^ ((row & 7) << 4)));
}

// ---------------- K1 (merged): bid<16 -> x = relu(r@W1^T+b1) (bf16 out);
//                  bid>=16 -> r_ol = r@b2_2d^T (f32 out). K=512, 256x128 tile. ----------------
template<int ROWS>
static __device__ __forceinline__ void stage_tile(char* ldsbase, const float* __restrict__ src,
                                                  int ld, int tid){
  #pragma unroll
  for (int w = 0; w < ROWS/32; ++w){
    int g = w*512 + tid;
    int row = g >> 4, k8 = g & 15;
    const float* p = src + (size_t)row*ld + k8*8;
    floatx4 v0 = *(const floatx4*)p;
    floatx4 v1 = *(const floatx4*)(p+4);
    *(short8*)(ldsbase + row*256 + ((k8*16) ^ ((row & 15) << 4))) = cvt8_pk(v0, v1);
  }
}

__global__ __launch_bounds__(512)
void gemm_two(const float* __restrict__ r, const float* __restrict__ W1,
              const float* __restrict__ b1, const float* __restrict__ b2,
              unsigned short* __restrict__ x_bf, float* __restrict__ r_ol){
  __shared__ char smem[98304];
  char* At = smem;            // [256][128] bf16 swz
  char* Bt = smem + 65536;    // [128][128] bf16 swz
  const int tid  = threadIdx.x;
  const int lane = tid & 63, w = tid >> 6;
  const int wm = w & 3, wn = w >> 2;
  const int bid0 = blockIdx.x;
  const int mode = bid0 >> 4;            // 0: x-GEMM, 1: bias-GEMV
  const int bid  = bid0 & 15;
  const float* Bsrc = mode ? b2 : W1;
  const int t0 = (bid & 3) * 256;
  const int c0 = (bid >> 2) * 128;
  const int rbase = wm*64, cbase = wn*64;

  floatx4 acc[4][4];
  #pragma unroll
  for (int i=0;i<4;++i)
    #pragma unroll
    for (int j=0;j<4;++j) acc[i][j] = floatx4{0.f,0.f,0.f,0.f};

  for (int kb = 0; kb < 4; ++kb){
    __syncthreads();
    stage_tile<256>(At, r + (size_t)t0*512 + kb*128, 512, tid);
    stage_tile<128>(Bt, Bsrc + (size_t)c0*512 + kb*128, 512, tid);
    __syncthreads();
    #pragma unroll
    for (int ks = 0; ks < 4; ++ks){
      const int kbyte = (ks*32 + (lane>>4)*8) * 2;
      short8 af[4], bfr[4];
      #pragma unroll
      for (int mi=0; mi<4; ++mi) af[mi] = frag_ld(At, rbase + mi*16 + (lane&15), kbyte);
      #pragma unroll
      for (int ni=0; ni<4; ++ni) bfr[ni] = frag_ld(Bt, cbase + ni*16 + (lane&15), kbyte);
      #pragma unroll
      for (int mi=0; mi<4; ++mi)
        #pragma unroll
        for (int ni=0; ni<4; ++ni)
          acc[mi][ni] = __builtin_amdgcn_mfma_f32_16x16x32_bf16(af[mi], bfr[ni], acc[mi][ni], 0,0,0);
    }
  }
  #pragma unroll
  for (int mi=0; mi<4; ++mi){
    #pragma unroll
    for (int ni=0; ni<4; ++ni){
      #pragma unroll
      for (int rg=0; rg<4; ++rg){
        int t = t0 + rbase + mi*16 + (lane>>4)*4 + rg;
        int c = c0 + cbase + ni*16 + (lane&15);
        float v = acc[mi][ni][rg];
        if (mode == 0){
          v += b1[c]; v = v > 0.f ? v : 0.f;
          x_bf[(size_t)t*512 + c] = f2bf(v);
        } else {
          r_ol[(size_t)t*512 + c] = v;
        }
      }
    }
  }
}

// ---------------- K2: r11 structure WITH setprio (r18 A/B: setprio = +10% here) ----------------
// Grid 256: xr=bid&7 (XCD), idx=bid>>3: m=idx&3, gh=idx>>2; g=xr+8*gh; ht=g&3, ns=g>>2.
// Block: M=256 x N=128, 32 n, BK=128 (kb2 0..3) -> 128 bodies. 8 waves (4M x 2N), tile 64x64.
__global__ __launch_bounds__(512)
void k2_fold(const unsigned short* __restrict__ xbf, const float* __restrict__ r,
             const float* __restrict__ W2, float* __restrict__ r_ol){
  __shared__ char smem[147456];  // A[256][256B] @0; B dbuf 2x[128][256B] @65536; RT2 bf16[32][256] @131072
  unsigned short* RT2 = (unsigned short*)(smem + 131072);
  const int tid  = threadIdx.x;
  const int lane = tid & 63, w = tid >> 6;
  const int wm = w & 3, wn = w >> 2;       // 8 waves: 4M x 2N, wave tile 64x64
  const int bid = blockIdx.x;
  const int xr = bid & 7, idx = bid >> 3;
  const int m  = idx & 3, gh = idx >> 2;   // gh 0..7
  const int g  = xr + 8*gh;                // 0..63
  const int ht = g & 3, ns = g >> 2;       // ns 0..15
  const int t0 = m*256, h0 = ht*128, n0 = ns*32;

  // prologue: RT2[n][row] = bf16(r[t0+row, n0+n])
  #pragma unroll
  for (int i = 0; i < 16; ++i){
    int e = i*512 + tid; int row = e >> 5, c = e & 31;
    RT2[c*256 + row] = f2bf(r[(size_t)(t0+row)*512 + n0 + c]);
  }

  floatx4 acc[4][4];
  #pragma unroll
  for (int i=0;i<4;++i)
    #pragma unroll
    for (int j=0;j<4;++j) acc[i][j] = floatx4{0.f,0.f,0.f,0.f};

  floatx4 lb[8];

  // A stage: coalesced. row=(tid>>4)+j*32, chunk=(tid&15) of 16B. Wave instr: 4 full rows.
  auto stageA = [&](int kb2){
    const int chunk = tid & 15, rbase_ = tid >> 4;
    #pragma unroll
    for (int j = 0; j < 8; ++j){
      const int row = rbase_ + j*32;
      short8 v = *(const short8*)(xbf + (size_t)(t0+row)*512 + kb2*128 + chunk*8);
      *(short8*)(smem + row*256 + (((chunk ^ (row & 15)) << 4))) = v;
    }
  };
  // B stage: coalesced. row=(tid>>5)+j*16, col=(tid&31)*16B. Wave instr: 2 full rows x 512B.
  auto issueB = [&](int n, int kb2){
    const int c16 = tid & 31, rb = tid >> 5;
    const float* base = W2 + (size_t)(n0+n)*512 + (size_t)kb2*128 + c16*4;
    #pragma unroll
    for (int j = 0; j < 8; ++j)
      lb[j] = *(const floatx4*)(base + (size_t)(h0 + rb + j*16)*262144);
  };
  auto cvtB = [&](char* Bb){
    const int c8 = tid & 31, rb = tid >> 5;
    #pragma unroll
    for (int j = 0; j < 8; ++j){
      const int row = rb + j*16;
      const int byte = (((c8 >> 1) ^ (row & 15)) << 4) | ((c8 & 1) << 3);
      *(short4v*)(Bb + row*256 + byte) = cvt4(lb[j]);
    }
  };
  auto compute_fold = [&](const char* Bb, int n){
    float rvv[4][4];
    #pragma unroll
    for (int mi = 0; mi < 4; ++mi){
      const int rrow = wm*64 + mi*16 + (lane>>4)*4;
      short4v tv = *(const short4v*)(RT2 + n*256 + rrow);
      #pragma unroll
      for (int j = 0; j < 4; ++j) rvv[mi][j] = bf2f((unsigned short)tv[j]);
    }
    floatx4 ct[4][4];
    #pragma unroll
    for (int ks = 0; ks < 4; ++ks){
      const int kbyte = ks*64 + (lane>>4)*16;
      short8 af[4], bfr[4];
      #pragma unroll
      for (int mi=0; mi<4; ++mi) af[mi] = frag_ld(smem, wm*64 + mi*16 + (lane&15), kbyte);
      #pragma unroll
      for (int ni=0; ni<4; ++ni) bfr[ni] = frag_ld(Bb, wn*64 + ni*16 + (lane&15), kbyte);
      __builtin_amdgcn_s_setprio(1);
      #pragma unroll
      for (int mi=0; mi<4; ++mi)
        #pragma unroll
        for (int ni=0; ni<4; ++ni)
          ct[mi][ni] = __builtin_amdgcn_mfma_f32_16x16x32_bf16(
              af[mi], bfr[ni], (ks==0) ? floatx4{0.f,0.f,0.f,0.f} : ct[mi][ni], 0,0,0);
      __builtin_amdgcn_s_setprio(0);
    }
    #pragma unroll
    for (int mi=0; mi<4; ++mi)
      #pragma unroll
      for (int ni=0; ni<4; ++ni){
        acc[mi][ni][0] += rvv[mi][0] * ct[mi][ni][0];
        acc[mi][ni][1] += rvv[mi][1] * ct[mi][ni][1];
        acc[mi][ni][2] += rvv[mi][2] * ct[mi][ni][2];
        acc[mi][ni][3] += rvv[mi][3] * ct[mi][ni][3];
      }
  };

  // prologue
  stageA(0);
  issueB(0, 0);
  cvtB(smem + 65536);
  __syncthreads();

  int cur = 0;
  for (int kb2 = 0; kb2 < 4; ++kb2){
    for (int n = 0; n < 32; ++n){
      const int bi = kb2*32 + n;
      if (bi < 127){
        const int nn = (n == 31) ? 0 : n + 1;
        const int nk = (n == 31) ? kb2 + 1 : kb2;
        issueB(nn, nk);
      }
      compute_fold(smem + 65536 + cur*32768, n);
      if (bi < 127) cvtB(smem + 65536 + (cur^1)*32768);
      __syncthreads();
      cur ^= 1;
    }
    if (kb2 < 3){
      stageA(kb2 + 1);   // A-LDS rewrite only at kb2 boundary, behind its own barrier
      __syncthreads();
    }
  }

  #pragma unroll
  for (int ni = 0; ni < 4; ++ni){
    const int h = h0 + wn*64 + ni*16 + (lane & 15);
    #pragma unroll
    for (int mi = 0; mi < 4; ++mi){
      #pragma unroll
      for (int rg = 0; rg < 4; ++rg){
        const int t = t0 + wm*64 + mi*16 + (lane >> 4)*4 + rg;
        atomicAdd(&r_ol[(size_t)t*512 + h], acc[mi][ni][rg]);
      }
    }
  }
}

// ---------------- K3: logits = r_ol @ Wout^T + bout (K=512), m SLOWEST ----------------
// Grid 1000: c = bid%250, m = bid/250 -> Wout streamed from HBM once, L3-hit after.
__global__ __launch_bounds__(512, 2)
void gemm_out(const float* __restrict__ Asrc, const float* __restrict__ Bsrc,
              const float* __restrict__ bias, float* __restrict__ out){
  __shared__ char smem[98304];   // A dbuf 2x[256][128B] swz, B dbuf 2x[128][128B] swz
  const int tid  = threadIdx.x;
  const int lane = tid & 63, w = tid >> 6;
  const int wm = w & 3, wn = w >> 2;
  const int bid = blockIdx.x;
  const int t0 = (bid / 250) * 256;
  const int c0 = (bid % 250) * 128;

  floatx4 acc[4][4];
  #pragma unroll
  for (int i=0;i<4;++i)
    #pragma unroll
    for (int j=0;j<4;++j) acc[i][j] = floatx4{0.f,0.f,0.f,0.f};

  floatx4 la[8], lb[4];
  const int r16 = tid >> 4, c4 = tid & 15;

  auto issue = [&](int s){
    const int K0 = s*64;
    #pragma unroll
    for (int it=0; it<8; ++it){
      int row = it*32 + r16;
      la[it] = *(const floatx4*)(Asrc + (size_t)(t0+row)*512 + K0 + c4*4);
    }
    #pragma unroll
    for (int it=0; it<4; ++it){
      int row = it*32 + r16;
      lb[it] = *(const floatx4*)(Bsrc + (size_t)(c0+row)*512 + K0 + c4*4);
    }
  };
  auto write_buf = [&](int buf){
    char* ad = smem + buf*32768;
    #pragma unroll
    for (int it=0; it<8; ++it){
      int row = it*32 + r16;
      *(short4v*)(ad + row*128 + ((c4*8) ^ ((row & 7) << 4))) = cvt4(la[it]);
    }
    char* bd = smem + 65536 + buf*16384;
    #pragma unroll
    for (int it=0; it<4; ++it){
      int row = it*32 + r16;
      *(short4v*)(bd + row*128 + ((c4*8) ^ ((row & 7) << 4))) = cvt4(lb[it]);
    }
  };
  auto compute = [&](int buf){
    const char* Ab = smem + buf*32768;
    const char* Bb = smem + 65536 + buf*16384;
    #pragma unroll
    for (int ks = 0; ks < 2; ++ks){
      const int kbyte = ks*64 + (lane >> 4)*16;
      short8 af[4], bfr[4];
      #pragma unroll
      for (int mi = 0; mi < 4; ++mi) af[mi] = frag_ld64(Ab, wm*64 + mi*16 + (lane&15), kbyte);
      #pragma unroll
      for (int ni = 0; ni < 4; ++ni) bfr[ni] = frag_ld64(Bb, wn*64 + ni*16 + (lane&15), kbyte);
      __builtin_amdgcn_s_setprio(1);
      #pragma unroll
      for (int mi = 0; mi < 4; ++mi)
        #pragma unroll
        for (int ni = 0; ni < 4; ++ni)
          acc[mi][ni] = __builtin_amdgcn_mfma_f32_16x16x32_bf16(af[mi], bfr[ni], acc[mi][ni], 0,0,0);
      __builtin_amdgcn_s_setprio(0);
    }
  };

  issue(0);
  write_buf(0);
  __syncthreads();
  for (int s = 0; s < 8; ++s){
    const int cur = s & 1;
    if (s < 7) issue(s + 1);
    compute(cur);
    if (s < 7){
      write_buf(cur ^ 1);
      __syncthreads();
    }
  }

  #pragma unroll
  for (int ni = 0; ni < 4; ++ni){
    const int c = c0 + wn*64 + ni*16 + (lane & 15);
    const float bv = bias[c];
    #pragma unroll
    for (int mi = 0; mi < 4; ++mi){
      #pragma unroll
      for (int rg = 0; rg < 4; ++rg){
        const int t = t0 + wm*64 + mi*16 + (lane >> 4)*4 + rg;
        out[(size_t)t*32000 + c] = acc[mi][ni][rg] + bv;
      }
    }
  }
}

extern "C" void kernel_launch(void* const* d_in, const int* in_sizes, int n_in,
                              void* d_out, int out_size, void* d_ws, size_t ws_size,
                              hipStream_t stream) {
  const float* r    = (const float*)d_in[0];   // [1024][512]
  const float* W1   = (const float*)d_in[1];   // [512][512]
  const float* b1   = (const float*)d_in[2];   // [512]
  const float* W2   = (const float*)d_in[3];   // [262144][512]
  const float* b2   = (const float*)d_in[4];   // [262144] == [512 h][512 n]
  const float* Wout = (const float*)d_in[5];   // [32000][512]
  const float* bout = (const float*)d_in[6];   // [32000]
  float* logits = (float*)d_out;               // [1024][32000]

  unsigned short* x_bf = (unsigned short*)d_ws;                 // 1 MiB bf16
  float* r_ol = (float*)((char*)d_ws + 1024*512*2);             // 2 MiB f32

  // merged: x = relu(r@W1^T+b1) -> bf16  AND  r_ol = r@b2_2d^T (atomic-target init)
  gemm_two<<<32, 512, 0, stream>>>(r, W1, b1, b2, x_bf, r_ol);
  // r_ol += fold-structured big GEMM (r11 structure + setprio)
  k2_fold<<<256, 512, 0, stream>>>(x_bf, r, W2, r_ol);
  // logits = r_ol @ Wout^T + bout (m-slowest for Wout L3 residency)
  gemm_out<<<1000, 512, 0, stream>>>(r_ol, Wout, bout, logits);
}